// Round 5
// baseline (82.633 us; speedup 1.0000x reference)
//
#include <hip/hip_runtime.h>
#include <hip/hip_bf16.h>
#include <math.h>

#define B_   4
#define T1_  4096
#define T2_  512
#define IC_  32
#define OC_  64

typedef unsigned short u16;
typedef unsigned int   u32;
typedef __attribute__((ext_vector_type(8))) short  short8;   // 8 bf16 = 4 VGPRs
typedef __attribute__((ext_vector_type(4))) float  float4v;  // MFMA C/D frag

__device__ __forceinline__ u16 f2bf(float f) {
    union { u32 u; float f; } v; v.f = f;
    u32 u = v.u;
    return (u16)((u + 0x7FFFu + ((u >> 16) & 1u)) >> 16);    // RNE
}
__device__ __forceinline__ float bfl(u32 d) {
    union { u32 u; float f; } v; v.u = d << 16; return v.f;
}
__device__ __forceinline__ float bfh(u32 d) {
    union { u32 u; float f; } v; v.u = d & 0xffff0000u; return v.f;
}
// pack high halves of two fp32 (truncation) into one dword of 2 bf16
__device__ __forceinline__ u32 pk2(float lo, float hi) {
    return __builtin_amdgcn_perm(__float_as_uint(hi), __float_as_uint(lo), 0x07060302);
}
__device__ __forceinline__ short8 packbf(float4 f0, float4 f1) {
    union { u32 d[4]; short8 s; } r;
    r.d[0] = pk2(f0.x, f0.y); r.d[1] = pk2(f0.z, f0.w);
    r.d[2] = pk2(f1.x, f1.y); r.d[3] = pk2(f1.z, f1.w);
    return r.s;
}

#define PI_F 3.14159265358979323846f

// ---------------------------------------------------------------------------
// Fully fused: per block = 8 bt rows, 1024 threads (16 waves), grid 256.
//   A: decode index -> (i0, f) per bt.
//   B: stage x-windows bf16 transposed [bt][c][68-pad] into buf; compute
//      fractional-delay filter wf[bt][64] (closed form of irfft(rfft*shift)).
//   C: interp — rotated register window, 1024 unrolled FMA/thread, write
//      yt[bt][2056 bf16, XOR-swizzled] into buf (union, after barrier).
//   D: MFMA gemm — A-frags from yt (LDS), B-frags from fp32 kern (global,
//      L2-resident) with perm-truncated bf16. M=8 (rows 8..15 zeroed),
//      K split across 16 waves, partials -> red[16][8][68] in buf (union).
//   E: sum 16 partials + bias -> out.
// ---------------------------------------------------------------------------
__global__ __launch_bounds__(1024) void fused_kernel(
        const float* __restrict__ x, const float* __restrict__ index,
        const float* __restrict__ kern, const float* __restrict__ bias,
        float* __restrict__ out)
{
    __shared__ __align__(16) u32 buf[8704];      // 34,816 B: xw / yt / red union
    __shared__ __align__(16) float wf[8][64];    // filters
    __shared__ int   ip8[8];
    __shared__ float fr8[8];

    const int tid = threadIdx.x;
    const int bt0 = blockIdx.x * 8;

    // ---- stage A: per-bt index decode ----
    if (tid < 8) {
        float fidx = index[bt0 + tid];
        float flo  = floorf(fidx);
        ip8[tid] = (int)flo;
        fr8[tid] = fidx - flo;
    }
    __syncthreads();

    // ---- stage B: windows (bf16, transposed [bt][c][68]) + filters ----
    {
        const int bt = tid >> 7;            // 0..7
        const int r  = tid & 127;
        const int c0 = (r & 15) * 2;        // even channel
        const int k8 = (r >> 4) * 8;        // 0,8,...,56
        const int b  = (bt0 + bt) >> 9;     // T2_ = 512
        const int i0 = ip8[bt];
        u32 pk[2][4];
        #pragma unroll
        for (int kk = 0; kk < 8; ++kk) {
            int pos = i0 + k8 + kk - 32;
            float vx = 0.f, vy = 0.f;
            if (pos >= 0 && pos < T1_) {
                const float2 v = *(const float2*)(x + ((size_t)(b * T1_ + pos) * IC_ + c0));
                vx = v.x; vy = v.y;
            }
            u32 bx = f2bf(vx), by = f2bf(vy);
            if (kk & 1) { pk[0][kk >> 1] |= bx << 16; pk[1][kk >> 1] |= by << 16; }
            else        { pk[0][kk >> 1]  = bx;       pk[1][kk >> 1]  = by; }
        }
        u16* xw = (u16*)buf;
        #pragma unroll
        for (int cc = 0; cc < 2; ++cc) {
            u32* p = (u32*)(xw + (size_t)bt * 2176 + (c0 + cc) * 68 + k8);
            *(uint2*)(p)     = make_uint2(pk[cc][0], pk[cc][1]);
            *(uint2*)(p + 2) = make_uint2(pk[cc][2], pk[cc][3]);
        }
    }
    if (tid < 512) {
        // w[j] = D(j+f), D(u) = sin(pi u) cos(pi u/64) / (64 sin(pi u/64))
        const int bt = tid >> 6, j = tid & 63;
        const float f = fr8[bt];
        float wj;
        if (f <= 0.0f) {
            wj = (j == 0) ? 1.0f : 0.0f;
        } else {
            float spf = sinf(PI_F * f);                  // sin(pi(j+f)) = (-1)^j sin(pi f)
            float a   = PI_F * ((float)j + f) * (1.0f / 64.0f);
            wj = ((j & 1) ? -spf : spf) * cosf(a) / (64.0f * sinf(a));
        }
        wf[bt][j] = wj;
    }
    __syncthreads();

    // ---- stage C1: rotated window (bf16 LDS -> fp32 regs) ----
    const int cbt = tid >> 7;               // 0..7
    const int cch = (tid >> 2) & 31;        // channel 0..31
    const int sq  = tid & 3;
    const int s0  = sq * 16;
    float xr[64];                           // xr[t] = xw[(s0+t)&63]
    {
        const u16* row = (const u16*)buf + (size_t)cbt * 2176 + cch * 68;
        #pragma unroll
        for (int i = 0; i < 16; ++i) {
            int k = (s0 + i * 4) & 63;      // 4-aligned, no wrap inside uint2
            uint2 v = *(const uint2*)(row + k);
            xr[i*4+0] = bfl(v.x); xr[i*4+1] = bfh(v.x);
            xr[i*4+2] = bfl(v.y); xr[i*4+3] = bfh(v.y);
        }
    }
    __syncthreads();                        // xw dead -> buf becomes yt

    // ---- stage C2: interp FMA + swizzled yt store ----
    {
        float acc[16];
        #pragma unroll
        for (int r = 0; r < 16; ++r) acc[r] = 0.f;
        #pragma unroll
        for (int jq = 0; jq < 16; ++jq) {
            const float4 wv = *(const float4*)&wf[cbt][jq * 4];   // broadcast
            #pragma unroll
            for (int jj = 0; jj < 4; ++jj) {
                const float wj = (jj==0)?wv.x:(jj==1)?wv.y:(jj==2)?wv.z:wv.w;
                const int j = jq * 4 + jj;
                #pragma unroll
                for (int r = 0; r < 16; ++r)
                    acc[r] += wj * xr[(j + r) & 63];  // static index after unroll
            }
        }
        u32 od[8];
        #pragma unroll
        for (int i = 0; i < 8; ++i)
            od[i] = (u32)f2bf(acc[2*i]) | ((u32)f2bf(acc[2*i+1]) << 16);
        const int key = (cch & 7) << 2;
        u32* base = buf + (size_t)cbt * 1028 + cch * 32;
        *(uint4*)(base + (((sq*8) + 0) ^ key)) = make_uint4(od[0], od[1], od[2], od[3]);
        *(uint4*)(base + (((sq*8) + 4) ^ key)) = make_uint4(od[4], od[5], od[6], od[7]);
    }
    __syncthreads();                        // yt complete

    // ---- stage D: MFMA gemm, K split across 16 waves ----
    const int w    = tid >> 6;              // wave 0..15: kb in [4w, 4w+4)
    const int lane = tid & 63;
    const int nm   = lane & 15;
    const int q    = lane >> 4;
    short8 afr[4];
    #pragma unroll
    for (int i = 0; i < 4; ++i) {
        const int kb = w * 4 + i;
        const int cA = kb >> 1;
        const u32* p = buf + (size_t)(nm & 7) * 1028 + cA * 32
                     + ((((kb & 1) * 16) + q * 4) ^ ((cA & 7) << 2));
        union { uint4 u; short8 s; } cvt;
        cvt.u = *(const uint4*)p;
        const short8 zz = {0,0,0,0,0,0,0,0};
        afr[i] = (nm < 8) ? cvt.s : zz;     // M=8: zero rows 8..15
    }
    __syncthreads();                        // yt dead -> buf becomes red

    float4v a0 = {0,0,0,0}, a1 = {0,0,0,0}, a2 = {0,0,0,0}, a3 = {0,0,0,0};
    #pragma unroll
    for (int i = 0; i < 4; ++i) {
        const int kb = w * 4 + i;
        const float* kp = kern + (size_t)nm * 2048 + kb * 32 + q * 8;
        float4 f0, f1;
        f0 = *(const float4*)(kp);
        f1 = *(const float4*)(kp + 4);
        a0 = __builtin_amdgcn_mfma_f32_16x16x32_bf16(afr[i], packbf(f0, f1), a0, 0, 0, 0);
        f0 = *(const float4*)(kp + 16 * 2048);
        f1 = *(const float4*)(kp + 16 * 2048 + 4);
        a1 = __builtin_amdgcn_mfma_f32_16x16x32_bf16(afr[i], packbf(f0, f1), a1, 0, 0, 0);
        f0 = *(const float4*)(kp + 32 * 2048);
        f1 = *(const float4*)(kp + 32 * 2048 + 4);
        a2 = __builtin_amdgcn_mfma_f32_16x16x32_bf16(afr[i], packbf(f0, f1), a2, 0, 0, 0);
        f0 = *(const float4*)(kp + 48 * 2048);
        f1 = *(const float4*)(kp + 48 * 2048 + 4);
        a3 = __builtin_amdgcn_mfma_f32_16x16x32_bf16(afr[i], packbf(f0, f1), a3, 0, 0, 0);
    }
    {
        float* red = (float*)buf;           // [16][8][68]
        if (q < 2) {                        // C rows 0..7 live in lanes 0..31
            #pragma unroll
            for (int r = 0; r < 4; ++r) {
                const int row = q * 4 + r;
                float* rp = red + (size_t)(w * 8 + row) * 68 + nm;
                rp[0]  = a0[r];
                rp[16] = a1[r];
                rp[32] = a2[r];
                rp[48] = a3[r];
            }
        }
    }
    __syncthreads();

    // ---- stage E: reduce 16 K-partials + bias ----
    if (tid < 512) {
        const int m = tid >> 6, o = tid & 63;
        float s = bias[o];
        const float* red = (const float*)buf;
        #pragma unroll
        for (int w2 = 0; w2 < 16; ++w2)
            s += red[(size_t)(w2 * 8 + m) * 68 + o];
        out[(size_t)(bt0 + m) * 64 + o] = s;
    }
}

// ---------------------------------------------------------------------------
extern "C" void kernel_launch(void* const* d_in, const int* in_sizes, int n_in,
                              void* d_out, int out_size, void* d_ws, size_t ws_size,
                              hipStream_t stream)
{
    const float* x     = (const float*)d_in[0];   // (4,4096,32) fp32
    const float* index = (const float*)d_in[1];   // (4,512) fp32
    const float* kern  = (const float*)d_in[2];   // (64,32,64) fp32
    const float* bias  = (const float*)d_in[3];   // (64,) fp32
    float* out = (float*)d_out;                   // (4,512,64) fp32

    fused_kernel<<<dim3(B_ * T2_ / 8), dim3(1024), 0, stream>>>(x, index, kern, bias, out);
}

// Round 6
// 75.488 us; speedup vs baseline: 1.0947x; 1.0947x over previous
//
#include <hip/hip_runtime.h>
#include <hip/hip_bf16.h>
#include <math.h>

#define B_   4
#define T1_  4096
#define T2_  512
#define IC_  32
#define OC_  64
#define KS_  64

typedef unsigned short u16;
typedef unsigned int   u32;
typedef __attribute__((ext_vector_type(8))) short  short8;   // 8 bf16 = 4 VGPRs
typedef __attribute__((ext_vector_type(4))) float  float4v;  // MFMA C/D frag

__device__ __forceinline__ u16 f2bf(float f) {
    union { u32 u; float f; } v; v.f = f;
    u32 u = v.u;
    return (u16)((u + 0x7FFFu + ((u >> 16) & 1u)) >> 16);    // RNE
}

#define PI_F 3.14159265358979323846f

// ---------------------------------------------------------------------------
// K1: fused prep + interp (R4-validated).
//   blocks [0,64):   prep — kernel (o,c,s) fp32 -> Bsz bf16 in MFMA B-frag
//                    order: Bsz[(cs>>3)*512 + o*8 + (cs&7)], cs = c*64+s.
//   blocks [64,1088): interp — 2 bt rows per block (bt = 2*p2, 2*p2+1,
//                    p2 = blockIdx-64; runs on XCD p2%8). Fractional-delay
//                    filter w[64] (closed form of irfft(rfft(k)*shift), incl
//                    Nyquist cos term) circularly applied to 64x32 x-window.
//                    Y[bt][cs=c*64+s] bf16 (A-matrix for MFMA gemm).
// ---------------------------------------------------------------------------
__global__ __launch_bounds__(256) void prep_interp_kernel(
        const float* __restrict__ x, const float* __restrict__ index,
        const float* __restrict__ kern, u16* __restrict__ Y,
        u16* __restrict__ Bsz)
{
    __shared__ __align__(16) float xwT[2][IC_][68];  // [half][c][k], pad 68
    __shared__ __align__(16) float wsh[2][64];

    const int tid = threadIdx.x;

    if (blockIdx.x < 64) {                  // ---- prep branch ----
        int gid = blockIdx.x * 256 + tid;   // 0..16383
        int o   = gid & 63;
        int cs8 = gid >> 6;                 // 0..255
        const float* p = kern + (size_t)o * 2048 + cs8 * 8;
        float4 a = *(const float4*)p;
        float4 b = *(const float4*)(p + 4);
        u16* q = Bsz + (size_t)cs8 * 512 + o * 8;
        *(ushort4*)(q)     = make_ushort4(f2bf(a.x), f2bf(a.y), f2bf(a.z), f2bf(a.w));
        *(ushort4*)(q + 4) = make_ushort4(f2bf(b.x), f2bf(b.y), f2bf(b.z), f2bf(b.w));
        return;
    }

    // ---- interp branch: this block handles bt = 2*p2 and 2*p2+1 ----
    const int p2 = blockIdx.x - 64;

    #pragma unroll
    for (int h = 0; h < 2; ++h) {
        const int bt = p2 * 2 + h;
        const int b  = bt >> 9;             // T2_ = 512
        float fidx = index[bt];
        float flo  = floorf(fidx);
        int   i0   = (int)flo;
        float f    = fidx - flo;

        // load 64x32 window (zero-padded) transposed into LDS [c][k]
        int e  = tid * 8;                   // e = k*32 + c0
        int k  = e >> 5;                    // 0..63
        int c0 = e & 31;
        int pos = i0 + k - 32;
        float vals[8];
        if (pos >= 0 && pos < T1_) {
            const float* p = x + ((size_t)(b * T1_ + pos) * IC_ + c0);
            float4 a = *(const float4*)p;
            float4 d = *(const float4*)(p + 4);
            vals[0]=a.x; vals[1]=a.y; vals[2]=a.z; vals[3]=a.w;
            vals[4]=d.x; vals[5]=d.y; vals[6]=d.z; vals[7]=d.w;
        } else {
            #pragma unroll
            for (int q = 0; q < 8; ++q) vals[q] = 0.0f;
        }
        #pragma unroll
        for (int q = 0; q < 8; ++q) xwT[h][c0 + q][k] = vals[q];

        // w[j] = D(j+f), D(u) = sin(pi u) cos(pi u/64) / (64 sin(pi u/64))
        if (tid < 64) {
            int j = tid;
            float wj;
            if (f <= 0.0f) {
                wj = (j == 0) ? 1.0f : 0.0f;
            } else {
                float spf = sinf(PI_F * f);     // sin(pi(j+f)) = (-1)^j sin(pi f)
                float a   = PI_F * ((float)j + f) * (1.0f / 64.0f);
                wj = ((j & 1) ? -spf : spf) * cosf(a) / (64.0f * sinf(a));
            }
            wsh[h][j] = wj;
        }
    }
    __syncthreads();

    // thread owns (h, c, s0..s0+15): 2*32*4 = 256 threads
    const int h   = tid >> 7;
    const int rem = tid & 127;
    const int c   = rem >> 2;               // 0..31
    const int s0  = (rem & 3) << 4;         // 0,16,32,48

    // rotated register window: xr[i] = xw[(s0+i)&63]
    float xr[64];
    #pragma unroll
    for (int q = 0; q < 16; ++q) {
        int idx = (s0 + q * 4) & 63;        // 4-aligned, no wrap inside float4
        const float4 v = *(const float4*)&xwT[h][c][idx];
        xr[q*4+0] = v.x; xr[q*4+1] = v.y; xr[q*4+2] = v.z; xr[q*4+3] = v.w;
    }

    float acc[16];
    #pragma unroll
    for (int r = 0; r < 16; ++r) acc[r] = 0.0f;

    #pragma unroll
    for (int jq = 0; jq < 16; ++jq) {
        const float4 wv = *(const float4*)&wsh[h][jq * 4];  // wave-uniform
        #pragma unroll
        for (int jj = 0; jj < 4; ++jj) {
            const float wj = (jj == 0) ? wv.x : (jj == 1) ? wv.y : (jj == 2) ? wv.z : wv.w;
            const int j = jq * 4 + jj;
            #pragma unroll
            for (int r = 0; r < 16; ++r)
                acc[r] += wj * xr[(j + r) & 63];   // static reg index after unroll
        }
    }

    // store Y[bt][c*64 + s0 .. +15] bf16 (32 B per thread, coalesced)
    const int bt = p2 * 2 + h;
    union { u16 u[8]; short8 v; } o0, o1;
    #pragma unroll
    for (int r = 0; r < 8; ++r) { o0.u[r] = f2bf(acc[r]); o1.u[r] = f2bf(acc[8 + r]); }
    u16* yp = Y + ((size_t)bt * 2048 + c * 64 + s0);
    *(short8*)(yp)     = o0.v;
    *(short8*)(yp + 8) = o1.v;
}

// ---------------------------------------------------------------------------
// K2 (MFMA gemm v3): out[bt][o] = Y[bt,:] @ B[:,o] + bias[o].
// 256 blocks x 512 threads (8 waves), 1 block/CU.
// XCD-local bt map: block g handles the 8 bt rows whose interp producer ran
// on XCD g%8:  p2(g,t) = (g&7) + 8*(4*(g>>3)+t), t=0..3; bt = 2*p2 + (0|1).
// Wave w owns kb in [8w, 8w+8) (K-slice of 256); FULL register prefetch of
// all 8 iterations (A 8x + B 32x dwordx4 in flight) then 32 MFMA.
// M=8 real rows (A rows 8..15 zeroed; D rows 8..15 discarded).
// A-frag: lane(m+16q): Y[bt(m)][kb*32+q*8 ..+7]          (16B global, L2-local)
// B-frag: lane(n+16q): Bsz[(kb*4+q)*512 + (nt*16+n)*8]   (16B global, L2-hot)
// C/D   : lane L, reg r -> row (L>>4)*4+r (bt), col L&15 (o within n-tile)
// ---------------------------------------------------------------------------
__global__ __launch_bounds__(512, 2) void gemm_kernel(const u16* __restrict__ Y,
                                                      const u16* __restrict__ Bsz,
                                                      const float* __restrict__ bias,
                                                      float* __restrict__ out)
{
    __shared__ float red[8][4][8][17];     // [wave][ntile][row][col], pad 17

    const int tid  = threadIdx.x;
    const int w    = tid >> 6;             // 0..7
    const int lane = tid & 63;
    const int nm   = lane & 15;
    const int q    = lane >> 4;
    const int g    = blockIdx.x;

    // bt for A-row nm (rows 0..7 real, 8..15 zero)
    const int rr  = nm & 7;
    const int p2  = (g & 7) + 8 * (4 * (g >> 3) + (rr >> 1));
    const int btA = 2 * p2 + (rr & 1);

    const int kb0 = w * 8;
    const u16* aptr = Y   + (size_t)btA * 2048 + kb0 * 32 + q * 8;
    const u16* bptr = Bsz + (size_t)kb0 * 2048 + q * 512 + nm * 8;

    // ---- full prefetch: 8 A-frags + 32 B-frags in flight ----
    short8 a[8], b[8][4];
    #pragma unroll
    for (int i = 0; i < 8; ++i) {
        a[i] = *(const short8*)(aptr + i * 32);
        #pragma unroll
        for (int n = 0; n < 4; ++n)
            b[i][n] = *(const short8*)(bptr + (size_t)i * 2048 + n * 128);
    }
    if (nm >= 8) {
        const short8 zz = {0,0,0,0,0,0,0,0};
        #pragma unroll
        for (int i = 0; i < 8; ++i) a[i] = zz;
    }

    float4v acc0 = {0,0,0,0}, acc1 = {0,0,0,0}, acc2 = {0,0,0,0}, acc3 = {0,0,0,0};
    #pragma unroll
    for (int i = 0; i < 8; ++i) {
        acc0 = __builtin_amdgcn_mfma_f32_16x16x32_bf16(a[i], b[i][0], acc0, 0, 0, 0);
        acc1 = __builtin_amdgcn_mfma_f32_16x16x32_bf16(a[i], b[i][1], acc1, 0, 0, 0);
        acc2 = __builtin_amdgcn_mfma_f32_16x16x32_bf16(a[i], b[i][2], acc2, 0, 0, 0);
        acc3 = __builtin_amdgcn_mfma_f32_16x16x32_bf16(a[i], b[i][3], acc3, 0, 0, 0);
    }

    // ---- cross-wave K reduction ----
    if (q < 2) {                           // D rows 0..7 live in lanes 0..31
        #pragma unroll
        for (int r = 0; r < 4; ++r) {
            const int row = q * 4 + r;
            red[w][0][row][nm] = acc0[r];
            red[w][1][row][nm] = acc1[r];
            red[w][2][row][nm] = acc2[r];
            red[w][3][row][nm] = acc3[r];
        }
    }
    __syncthreads();

    // ---- epilogue: 512 threads = 8 rows x 64 o ----
    {
        const int row = tid >> 6;          // 0..7
        const int o   = tid & 63;
        float s = bias[o];
        #pragma unroll
        for (int ww = 0; ww < 8; ++ww)
            s += red[ww][o >> 4][row][o & 15];
        const int p2o = (g & 7) + 8 * (4 * (g >> 3) + (row >> 1));
        const int bto = 2 * p2o + (row & 1);
        out[(size_t)bto * 64 + o] = s;
    }
}

// ---------------------------------------------------------------------------
extern "C" void kernel_launch(void* const* d_in, const int* in_sizes, int n_in,
                              void* d_out, int out_size, void* d_ws, size_t ws_size,
                              hipStream_t stream)
{
    const float* x     = (const float*)d_in[0];   // (4,4096,32) fp32
    const float* index = (const float*)d_in[1];   // (4,512) fp32
    const float* kern  = (const float*)d_in[2];   // (64,32,64) fp32
    const float* bias  = (const float*)d_in[3];   // (64,) fp32
    float* out = (float*)d_out;                   // (4,512,64) fp32

    u16* Y   = (u16*)d_ws;                                      // 2048*2048 bf16 = 8 MB
    u16* Bsz = (u16*)((char*)d_ws + (size_t)8 * 1024 * 1024);   // 256 KB

    prep_interp_kernel<<<dim3(64 + B_ * T2_ / 2), dim3(256), 0, stream>>>(x, index, kern, Y, Bsz);
    gemm_kernel<<<dim3(256), dim3(512), 0, stream>>>(Y, Bsz, bias, out);
}

// Round 7
// 72.173 us; speedup vs baseline: 1.1449x; 1.0459x over previous
//
#include <hip/hip_runtime.h>
#include <hip/hip_bf16.h>
#include <math.h>

#define B_   4
#define T1_  4096
#define T2_  512
#define IC_  32
#define OC_  64
#define KS_  64

typedef unsigned short u16;
typedef unsigned int   u32;
typedef __attribute__((ext_vector_type(8))) short  short8;   // 8 bf16 = 4 VGPRs
typedef __attribute__((ext_vector_type(4))) float  float4v;  // MFMA C/D frag

__device__ __forceinline__ u16 f2bf(float f) {
    union { u32 u; float f; } v; v.f = f;
    u32 u = v.u;
    return (u16)((u + 0x7FFFu + ((u >> 16) & 1u)) >> 16);    // RNE
}

#define PI_F 3.14159265358979323846f

// ---------------------------------------------------------------------------
// K1: fused prep + MFMA-interp.
//   blocks [0,64):    prep — kernel (o,c,s) fp32 -> Bsz bf16 in MFMA B-frag
//                     order: Bsz[(cs>>3)*512 + o*8 + (cs&7)], cs = c*64+s.
//   blocks [64,576):  interp — 4 bt per block, one WAVE per bt.
//     Y_bt(64x32) = W(f)(64x64 circulant) @ Xwin(64x32) via 16x16x32 MFMA.
//     W[s][k] = w[(k-s)&63], w = closed-form fractional-delay filter
//     (irfft(rfft(kernel)*phase), incl. Nyquist cos term).
//     Circulant property: A-frag(mt,kb) depends only on d=(2kb-mt)&3 ->
//     4 distinct A-frags, read from doubled fp32 w2[72] in LDS at lane
//     offset (16d + q*8 - m)&63 (b32, always 4B-aligned).
//     B-frags (X) load straight from global with clamp+mask. No barriers.
//     D: lane L, reg r -> s = mt*16 + (L>>4)*4 + r, c = nt*16 + (L&15);
//     store Y[bt][c*64+s] (8B dwordx2 per frag).
// ---------------------------------------------------------------------------
__global__ __launch_bounds__(256) void prep_interp_kernel(
        const float* __restrict__ x, const float* __restrict__ index,
        const float* __restrict__ kern, u16* __restrict__ Y,
        u16* __restrict__ Bsz)
{
    __shared__ __align__(16) float w2[4][76];   // doubled filter, per wave

    const int tid = threadIdx.x;

    if (blockIdx.x < 64) {                  // ---- prep branch ----
        int gid = blockIdx.x * 256 + tid;   // 0..16383
        int o   = gid & 63;
        int cs8 = gid >> 6;                 // 0..255
        const float* p = kern + (size_t)o * 2048 + cs8 * 8;
        float4 a = *(const float4*)p;
        float4 b = *(const float4*)(p + 4);
        u16* q = Bsz + (size_t)cs8 * 512 + o * 8;
        *(ushort4*)(q)     = make_ushort4(f2bf(a.x), f2bf(a.y), f2bf(a.z), f2bf(a.w));
        *(ushort4*)(q + 4) = make_ushort4(f2bf(b.x), f2bf(b.y), f2bf(b.z), f2bf(b.w));
        return;
    }

    // ---- interp branch ----
    const int pb   = blockIdx.x - 64;       // 0..511 (XCD = pb%8)
    const int wv   = tid >> 6;              // wave 0..3
    const int lane = tid & 63;
    const int bt   = pb * 4 + wv;
    const int b    = bt >> 9;               // T2_ = 512

    const float fidx = index[bt];
    const float flo  = floorf(fidx);
    const int   i0   = (int)flo;
    const float f    = fidx - flo;

    // filter: lane t computes w[t]; doubled into w2[wv][0..71]
    {
        const int t = lane;
        float wj;
        if (f <= 0.0f) {
            wj = (t == 0) ? 1.0f : 0.0f;
        } else {
            float spf = sinf(PI_F * f);              // sin(pi(t+f)) = (-1)^t sin(pi f)
            float a   = PI_F * ((float)t + f) * (1.0f / 64.0f);
            wj = ((t & 1) ? -spf : spf) * cosf(a) / (64.0f * sinf(a));
        }
        w2[wv][t] = wj;
        if (t < 8) w2[wv][64 + t] = wj;              // w2[64+t] = w[t]
    }
    // same-wave LDS write->read: compiler-inserted lgkmcnt, no barrier needed

    const int nm = lane & 15;               // m (A), n (B), col (D)
    const int q  = lane >> 4;               // quad

    // ---- 4 distinct A-frags (circulant W) ----
    short8 Afr[4];
    #pragma unroll
    for (int d = 0; d < 4; ++d) {
        const int o0 = (16 * d + q * 8 - nm) & 63;   // <= 63; +7 <= 70 < 72
        const float* wp = &w2[wv][o0];
        union { u16 u[8]; short8 s; } cv;
        #pragma unroll
        for (int j = 0; j < 8; ++j) cv.u[j] = f2bf(wp[j]);
        Afr[d] = cv.s;
    }

    // ---- 4 B-frags (X window) straight from global ----
    short8 Bfr[2][2];
    #pragma unroll
    for (int kb = 0; kb < 2; ++kb) {
        #pragma unroll
        for (int nt = 0; nt < 2; ++nt) {
            const int c = nt * 16 + nm;
            union { u16 u[8]; short8 s; } cv;
            #pragma unroll
            for (int j = 0; j < 8; ++j) {
                int pos = i0 - 32 + kb * 32 + q * 8 + j;
                int pc  = min(max(pos, 0), T1_ - 1);             // safe addr
                float v = x[(size_t)(b * T1_ + pc) * IC_ + c];
                v = ((unsigned)pos < (unsigned)T1_) ? v : 0.0f;  // zero-pad
                cv.u[j] = f2bf(v);
            }
            Bfr[kb][nt] = cv.s;
        }
    }

    // ---- 16 MFMA: acc[mt][nt] += Afr[(2kb-mt)&3] * Bfr[kb][nt] ----
    float4v acc[4][2];
    #pragma unroll
    for (int mt = 0; mt < 4; ++mt)
        #pragma unroll
        for (int nt = 0; nt < 2; ++nt)
            acc[mt][nt] = (float4v){0.f, 0.f, 0.f, 0.f};
    #pragma unroll
    for (int kb = 0; kb < 2; ++kb)
        #pragma unroll
        for (int mt = 0; mt < 4; ++mt) {
            const int d = (2 * kb - mt) & 3;
            #pragma unroll
            for (int nt = 0; nt < 2; ++nt)
                acc[mt][nt] = __builtin_amdgcn_mfma_f32_16x16x32_bf16(
                                  Afr[d], Bfr[kb][nt], acc[mt][nt], 0, 0, 0);
        }

    // ---- store Y[bt][c*64 + s] bf16 ----
    #pragma unroll
    for (int mt = 0; mt < 4; ++mt)
        #pragma unroll
        for (int nt = 0; nt < 2; ++nt) {
            const int c = nt * 16 + nm;
            const int s = mt * 16 + q * 4;
            u32 d0 = (u32)f2bf(acc[mt][nt][0]) | ((u32)f2bf(acc[mt][nt][1]) << 16);
            u32 d1 = (u32)f2bf(acc[mt][nt][2]) | ((u32)f2bf(acc[mt][nt][3]) << 16);
            *(uint2*)(Y + (size_t)bt * 2048 + c * 64 + s) = make_uint2(d0, d1);
        }
}

// ---------------------------------------------------------------------------
// K2 (MFMA gemm, R6-validated): out[bt][o] = Y[bt,:] @ B[:,o] + bias[o].
// 256 blocks x 512 threads (8 waves), 1 block/CU.
// XCD-local bt map (matches interp producer: bt-quad pb ran on XCD pb%8):
//   pb(g,row) = (g&7) + 8*(2*(g>>3) + (row>>2)); bt = 4*pb + (row&3).
// Wave w owns kb in [8w, 8w+8); FULL register prefetch then 32 MFMA.
// M=8 real rows (A rows 8..15 zeroed; D rows 8..15 discarded).
// ---------------------------------------------------------------------------
__global__ __launch_bounds__(512, 2) void gemm_kernel(const u16* __restrict__ Y,
                                                      const u16* __restrict__ Bsz,
                                                      const float* __restrict__ bias,
                                                      float* __restrict__ out)
{
    __shared__ float red[8][4][8][17];     // [wave][ntile][row][col], pad 17

    const int tid  = threadIdx.x;
    const int w    = tid >> 6;             // 0..7
    const int lane = tid & 63;
    const int nm   = lane & 15;
    const int q    = lane >> 4;
    const int g    = blockIdx.x;

    // bt for A-row nm (rows 0..7 real, 8..15 zero)
    const int rr  = nm & 7;
    const int pbA = (g & 7) + 8 * (2 * (g >> 3) + (rr >> 2));
    const int btA = 4 * pbA + (rr & 3);

    const int kb0 = w * 8;
    const u16* aptr = Y   + (size_t)btA * 2048 + kb0 * 32 + q * 8;
    const u16* bptr = Bsz + (size_t)kb0 * 2048 + q * 512 + nm * 8;

    // ---- full prefetch: 8 A-frags + 32 B-frags in flight ----
    short8 a[8], b[8][4];
    #pragma unroll
    for (int i = 0; i < 8; ++i) {
        a[i] = *(const short8*)(aptr + i * 32);
        #pragma unroll
        for (int n = 0; n < 4; ++n)
            b[i][n] = *(const short8*)(bptr + (size_t)i * 2048 + n * 128);
    }
    if (nm >= 8) {
        const short8 zz = {0,0,0,0,0,0,0,0};
        #pragma unroll
        for (int i = 0; i < 8; ++i) a[i] = zz;
    }

    float4v acc0 = {0,0,0,0}, acc1 = {0,0,0,0}, acc2 = {0,0,0,0}, acc3 = {0,0,0,0};
    #pragma unroll
    for (int i = 0; i < 8; ++i) {
        acc0 = __builtin_amdgcn_mfma_f32_16x16x32_bf16(a[i], b[i][0], acc0, 0, 0, 0);
        acc1 = __builtin_amdgcn_mfma_f32_16x16x32_bf16(a[i], b[i][1], acc1, 0, 0, 0);
        acc2 = __builtin_amdgcn_mfma_f32_16x16x32_bf16(a[i], b[i][2], acc2, 0, 0, 0);
        acc3 = __builtin_amdgcn_mfma_f32_16x16x32_bf16(a[i], b[i][3], acc3, 0, 0, 0);
    }

    // ---- cross-wave K reduction ----
    if (q < 2) {                           // D rows 0..7 live in lanes 0..31
        #pragma unroll
        for (int r = 0; r < 4; ++r) {
            const int row = q * 4 + r;
            red[w][0][row][nm] = acc0[r];
            red[w][1][row][nm] = acc1[r];
            red[w][2][row][nm] = acc2[r];
            red[w][3][row][nm] = acc3[r];
        }
    }
    __syncthreads();

    // ---- epilogue: 512 threads = 8 rows x 64 o ----
    {
        const int row = tid >> 6;          // 0..7
        const int o   = tid & 63;
        float s = bias[o];
        #pragma unroll
        for (int ww = 0; ww < 8; ++ww)
            s += red[ww][o >> 4][row][o & 15];
        const int pbo = (g & 7) + 8 * (2 * (g >> 3) + (row >> 2));
        const int bto = 4 * pbo + (row & 3);
        out[(size_t)bto * 64 + o] = s;
    }
}

// ---------------------------------------------------------------------------
extern "C" void kernel_launch(void* const* d_in, const int* in_sizes, int n_in,
                              void* d_out, int out_size, void* d_ws, size_t ws_size,
                              hipStream_t stream)
{
    const float* x     = (const float*)d_in[0];   // (4,4096,32) fp32
    const float* index = (const float*)d_in[1];   // (4,512) fp32
    const float* kern  = (const float*)d_in[2];   // (64,32,64) fp32
    const float* bias  = (const float*)d_in[3];   // (64,) fp32
    float* out = (float*)d_out;                   // (4,512,64) fp32

    u16* Y   = (u16*)d_ws;                                      // 2048*2048 bf16 = 8 MB
    u16* Bsz = (u16*)((char*)d_ws + (size_t)8 * 1024 * 1024);   // 256 KB

    prep_interp_kernel<<<dim3(64 + B_ * T2_ / 4), dim3(256), 0, stream>>>(x, index, kern, Y, Bsz);
    gemm_kernel<<<dim3(256), dim3(512), 0, stream>>>(Y, Bsz, bias, out);
}

// Round 8
// 71.965 us; speedup vs baseline: 1.1482x; 1.0029x over previous
//
#include <hip/hip_runtime.h>
#include <hip/hip_bf16.h>
#include <math.h>

#define B_   4
#define T1_  4096
#define T2_  512
#define IC_  32
#define OC_  64
#define KS_  64

typedef unsigned short u16;
typedef unsigned int   u32;
typedef __attribute__((ext_vector_type(8))) short  short8;   // 8 bf16 = 4 VGPRs
typedef __attribute__((ext_vector_type(4))) float  float4v;  // MFMA C/D frag

__device__ __forceinline__ u16 f2bf(float f) {
    union { u32 u; float f; } v; v.f = f;
    u32 u = v.u;
    return (u16)((u + 0x7FFFu + ((u >> 16) & 1u)) >> 16);    // RNE
}

#define PI_F 3.14159265358979323846f

// ---------------------------------------------------------------------------
// K1: fused prep + MFMA-interp (R7-validated).
//   blocks [0,64):    prep — kernel (o,c,s) fp32 -> Bsz bf16 in MFMA B-frag
//                     order: Bsz[(cs>>3)*512 + o*8 + (cs&7)], cs = c*64+s.
//   blocks [64,576):  interp — 4 bt per block, one WAVE per bt.
//     Y_bt(64x32) = W(f)(64x64 circulant) @ Xwin(64x32) via 16x16x32 MFMA.
//     W[s][k] = w[(k-s)&63], w = closed-form fractional-delay filter
//     (irfft(rfft(kernel)*phase), incl. Nyquist cos term).
//     Circulant: A-frag(mt,kb) depends only on d=(2kb-mt)&3 -> 4 distinct
//     A-frags from doubled fp32 w2[] in LDS at lane offset (16d+q*8-m)&63.
//     B-frags (X) load straight from global with clamp+mask. No barriers.
// ---------------------------------------------------------------------------
__global__ __launch_bounds__(256) void prep_interp_kernel(
        const float* __restrict__ x, const float* __restrict__ index,
        const float* __restrict__ kern, u16* __restrict__ Y,
        u16* __restrict__ Bsz)
{
    __shared__ __align__(16) float w2[4][76];   // doubled filter, per wave

    const int tid = threadIdx.x;

    if (blockIdx.x < 64) {                  // ---- prep branch ----
        int gid = blockIdx.x * 256 + tid;   // 0..16383
        int o   = gid & 63;
        int cs8 = gid >> 6;                 // 0..255
        const float* p = kern + (size_t)o * 2048 + cs8 * 8;
        float4 a = *(const float4*)p;
        float4 b = *(const float4*)(p + 4);
        u16* q = Bsz + (size_t)cs8 * 512 + o * 8;
        *(ushort4*)(q)     = make_ushort4(f2bf(a.x), f2bf(a.y), f2bf(a.z), f2bf(a.w));
        *(ushort4*)(q + 4) = make_ushort4(f2bf(b.x), f2bf(b.y), f2bf(b.z), f2bf(b.w));
        return;
    }

    // ---- interp branch ----
    const int pb   = blockIdx.x - 64;       // 0..511 (XCD = pb%8)
    const int wv   = tid >> 6;              // wave 0..3
    const int lane = tid & 63;
    const int bt   = pb * 4 + wv;
    const int b    = bt >> 9;               // T2_ = 512

    const float fidx = index[bt];
    const float flo  = floorf(fidx);
    const int   i0   = (int)flo;
    const float f    = fidx - flo;

    // filter: lane t computes w[t]; doubled into w2[wv][0..71]
    {
        const int t = lane;
        float wj;
        if (f <= 0.0f) {
            wj = (t == 0) ? 1.0f : 0.0f;
        } else {
            float spf = sinf(PI_F * f);              // sin(pi(t+f)) = (-1)^t sin(pi f)
            float a   = PI_F * ((float)t + f) * (1.0f / 64.0f);
            wj = ((t & 1) ? -spf : spf) * cosf(a) / (64.0f * sinf(a));
        }
        w2[wv][t] = wj;
        if (t < 8) w2[wv][64 + t] = wj;              // w2[64+t] = w[t]
    }
    // same-wave LDS write->read: compiler-inserted lgkmcnt, no barrier needed

    const int nm = lane & 15;               // m (A), n (B), col (D)
    const int q  = lane >> 4;               // quad

    // ---- 4 distinct A-frags (circulant W) ----
    short8 Afr[4];
    #pragma unroll
    for (int d = 0; d < 4; ++d) {
        const int o0 = (16 * d + q * 8 - nm) & 63;   // <= 63; +7 <= 70 < 72
        const float* wp = &w2[wv][o0];
        union { u16 u[8]; short8 s; } cv;
        #pragma unroll
        for (int j = 0; j < 8; ++j) cv.u[j] = f2bf(wp[j]);
        Afr[d] = cv.s;
    }

    // ---- 4 B-frags (X window) straight from global ----
    short8 Bfr[2][2];
    #pragma unroll
    for (int kb = 0; kb < 2; ++kb) {
        #pragma unroll
        for (int nt = 0; nt < 2; ++nt) {
            const int c = nt * 16 + nm;
            union { u16 u[8]; short8 s; } cv;
            #pragma unroll
            for (int j = 0; j < 8; ++j) {
                int pos = i0 - 32 + kb * 32 + q * 8 + j;
                int pc  = min(max(pos, 0), T1_ - 1);             // safe addr
                float v = x[(size_t)(b * T1_ + pc) * IC_ + c];
                v = ((unsigned)pos < (unsigned)T1_) ? v : 0.0f;  // zero-pad
                cv.u[j] = f2bf(v);
            }
            Bfr[kb][nt] = cv.s;
        }
    }

    // ---- 16 MFMA: acc[mt][nt] += Afr[(2kb-mt)&3] * Bfr[kb][nt] ----
    float4v acc[4][2];
    #pragma unroll
    for (int mt = 0; mt < 4; ++mt)
        #pragma unroll
        for (int nt = 0; nt < 2; ++nt)
            acc[mt][nt] = (float4v){0.f, 0.f, 0.f, 0.f};
    #pragma unroll
    for (int kb = 0; kb < 2; ++kb)
        #pragma unroll
        for (int mt = 0; mt < 4; ++mt) {
            const int d = (2 * kb - mt) & 3;
            #pragma unroll
            for (int nt = 0; nt < 2; ++nt)
                acc[mt][nt] = __builtin_amdgcn_mfma_f32_16x16x32_bf16(
                                  Afr[d], Bfr[kb][nt], acc[mt][nt], 0, 0, 0);
        }

    // ---- store Y[bt][c*64 + s] bf16 ----
    #pragma unroll
    for (int mt = 0; mt < 4; ++mt)
        #pragma unroll
        for (int nt = 0; nt < 2; ++nt) {
            const int c = nt * 16 + nm;
            const int s = mt * 16 + q * 4;
            u32 d0 = (u32)f2bf(acc[mt][nt][0]) | ((u32)f2bf(acc[mt][nt][1]) << 16);
            u32 d1 = (u32)f2bf(acc[mt][nt][2]) | ((u32)f2bf(acc[mt][nt][3]) << 16);
            *(uint2*)(Y + (size_t)bt * 2048 + c * 64 + s) = make_uint2(d0, d1);
        }
}

// ---------------------------------------------------------------------------
// K2 (MFMA gemm v4): out[bt][o] = Y[bt,:] @ B[:,o] + bias[o].
// 128 blocks x 512 threads (8 waves). M=16 FULL rows (no zero-padding waste;
// halves aggregate Bsz L2 re-read vs M=8: 64 -> 32 MB).
// XCD-local bt map (producer: bt-quad pb ran on XCD pb%8):
//   pb(g,r16) = (g&7) + 8*(4*(g>>3) + (r16>>2)); bt = 4*pb + (r16&3).
// Wave w owns kb in [8w, 8w+8); FULL register prefetch then 32 MFMA.
// A-frag: lane(m+16q): Y[bt(m)][kb*32+q*8 ..+7]          (16B, L2-local)
// B-frag: lane(n+16q): Bsz[(kb*4+q)*512 + (nt*16+n)*8]   (16B, L2-hot)
// C/D   : lane L, reg r -> row (L>>4)*4+r, col L&15 (o within n-tile)
// ---------------------------------------------------------------------------
__global__ __launch_bounds__(512, 2) void gemm_kernel(const u16* __restrict__ Y,
                                                      const u16* __restrict__ Bsz,
                                                      const float* __restrict__ bias,
                                                      float* __restrict__ out)
{
    __shared__ float red[8][4][16][17];    // [wave][ntile][row][col], pad 17

    const int tid  = threadIdx.x;
    const int w    = tid >> 6;             // 0..7
    const int lane = tid & 63;
    const int nm   = lane & 15;
    const int q    = lane >> 4;
    const int g    = blockIdx.x;           // 0..127

    // bt for A-row nm (all 16 rows real)
    const int pbA = (g & 7) + 8 * (4 * (g >> 3) + (nm >> 2));
    const int btA = 4 * pbA + (nm & 3);

    const int kb0 = w * 8;
    const u16* aptr = Y   + (size_t)btA * 2048 + kb0 * 32 + q * 8;
    const u16* bptr = Bsz + (size_t)kb0 * 2048 + q * 512 + nm * 8;

    // ---- full prefetch: 8 A-frags + 32 B-frags in flight ----
    short8 a[8], b[8][4];
    #pragma unroll
    for (int i = 0; i < 8; ++i) {
        a[i] = *(const short8*)(aptr + i * 32);
        #pragma unroll
        for (int n = 0; n < 4; ++n)
            b[i][n] = *(const short8*)(bptr + (size_t)i * 2048 + n * 128);
    }

    float4v acc0 = {0,0,0,0}, acc1 = {0,0,0,0}, acc2 = {0,0,0,0}, acc3 = {0,0,0,0};
    #pragma unroll
    for (int i = 0; i < 8; ++i) {
        acc0 = __builtin_amdgcn_mfma_f32_16x16x32_bf16(a[i], b[i][0], acc0, 0, 0, 0);
        acc1 = __builtin_amdgcn_mfma_f32_16x16x32_bf16(a[i], b[i][1], acc1, 0, 0, 0);
        acc2 = __builtin_amdgcn_mfma_f32_16x16x32_bf16(a[i], b[i][2], acc2, 0, 0, 0);
        acc3 = __builtin_amdgcn_mfma_f32_16x16x32_bf16(a[i], b[i][3], acc3, 0, 0, 0);
    }

    // ---- cross-wave K reduction (all 16 D rows real) ----
    #pragma unroll
    for (int r = 0; r < 4; ++r) {
        const int row = q * 4 + r;
        red[w][0][row][nm] = acc0[r];
        red[w][1][row][nm] = acc1[r];
        red[w][2][row][nm] = acc2[r];
        red[w][3][row][nm] = acc3[r];
    }
    __syncthreads();

    // ---- epilogue: 1024 outputs (16 rows x 64 o), 2 per thread ----
    #pragma unroll
    for (int e = tid; e < 1024; e += 512) {
        const int row = e >> 6;            // 0..15
        const int o   = e & 63;
        float s = bias[o];
        #pragma unroll
        for (int ww = 0; ww < 8; ++ww)
            s += red[ww][o >> 4][row][o & 15];
        const int pbo = (g & 7) + 8 * (4 * (g >> 3) + (row >> 2));
        const int bto = 4 * pbo + (row & 3);
        out[(size_t)bto * 64 + o] = s;
    }
}

// ---------------------------------------------------------------------------
extern "C" void kernel_launch(void* const* d_in, const int* in_sizes, int n_in,
                              void* d_out, int out_size, void* d_ws, size_t ws_size,
                              hipStream_t stream)
{
    const float* x     = (const float*)d_in[0];   // (4,4096,32) fp32
    const float* index = (const float*)d_in[1];   // (4,512) fp32
    const float* kern  = (const float*)d_in[2];   // (64,32,64) fp32
    const float* bias  = (const float*)d_in[3];   // (64,) fp32
    float* out = (float*)d_out;                   // (4,512,64) fp32

    u16* Y   = (u16*)d_ws;                                      // 2048*2048 bf16 = 8 MB
    u16* Bsz = (u16*)((char*)d_ws + (size_t)8 * 1024 * 1024);   // 256 KB

    prep_interp_kernel<<<dim3(64 + B_ * T2_ / 4), dim3(256), 0, stream>>>(x, index, kern, Y, Bsz);
    gemm_kernel<<<dim3(128), dim3(512), 0, stream>>>(Y, Bsz, bias, out);
}